// Round 1
// baseline (366.130 us; speedup 1.0000x reference)
//
#include <hip/hip_runtime.h>

// Problem constants (match reference)
constexpr int   T_STEPS = 64;
constexpr int   NN      = 2048;
constexpr float DT_TAU  = 0.1f;    // DT * TAU_MEM_INV
constexpr float V_TH_C  = 1.0f;
constexpr float TRC     = 0.05f;   // DT * TAU_PRE_INV == DT * TAU_POST_INV
constexpr float ETA     = 1e-3f;   // ETA_PLUS == ETA_MINUS

// 256 blocks x 512 threads (cooperative, 1 block/CU). Block b owns neurons
// [8b, 8b+8): their w rows (registers, 32 VGPR/lane), v, tpo. z and tp are
// replicated per block, reconstructed each step from the published spike bits.
// Cross-block traffic per step: ONE u32 per block (8 spike bits + step tag).
// Poll side: ONE wave per block, 64 lanes x global_load_dwordx4 (4 words/lane)
// -> 64 transactions/sweep/block vs the previous 256. sc0 sc1 = coherent read
// from the device coherence point (bypasses L1/L2), never stale.
constexpr int BLOCKS  = 256;
constexpr int THREADS = 512;
constexpr int ROWS_PER_BLOCK = NN / BLOCKS;   // 8
constexpr int CHUNKS = NN / 256;              // 8 float4 chunks per lane

typedef unsigned int uint4v __attribute__((ext_vector_type(4)));

__global__ __launch_bounds__(THREADS)
void snn_msg_kernel(const float* __restrict__ x,       // [T, N]
                    const float* __restrict__ w_in,    // [N, N] pristine (never written)
                    const float* __restrict__ tpre0,   // [N]
                    const float* __restrict__ tpost0,  // [N]
                    unsigned*    __restrict__ zpub,    // [2][BLOCKS] u32: (t+1)<<8 | bits
                    float*       __restrict__ out)     // [T, N] spikes
{
    const int bid  = blockIdx.x;
    const int tid  = threadIdx.x;
    const int wv   = tid >> 6;
    const int lane = tid & 63;
    const int row  = bid * ROWS_PER_BLOCK + wv;   // this wave's w row / owned neuron

    __shared__ __align__(16) float z_s[NN];       // replicated spike vector
    __shared__ __align__(16) float tp_s[NN];      // replicated pre-trace
    __shared__ __align__(16) float x_s[T_STEPS * ROWS_PER_BLOCK]; // all owned inputs (2 KB)
    __shared__ __align__(16) unsigned zw_s[BLOCKS];  // polled spike words
    __shared__ float tpo_s8[ROWS_PER_BLOCK];      // owned post-traces
    __shared__ float isyn_s8[ROWS_PER_BLOCK];     // owned synaptic currents (local!)

    // Replicated tp in registers (neurons 4*tid..4*tid+3), mirrored to LDS.
    float4 tp4 = ((const float4*)tpre0)[tid];
    ((float4*)tp_s)[tid] = tp4;

    // Stage ALL owned inputs x[t][8b..8b+8) into LDS once: removes the per-step
    // global load from wave 0's critical path.
    x_s[tid] = x[(size_t)(tid >> 3) * NN + bid * ROWS_PER_BLOCK + (tid & 7)];

    // Owner state on threads 0..7 (wave 0): v, tpo.
    float v_own = 0.0f, tpo_own = 0.0f;
    if (tid < ROWS_PER_BLOCK) {
        tpo_own = tpost0[bid * ROWS_PER_BLOCK + tid];
        isyn_s8[tid] = 0.0f;                       // step 0: i_syn = w @ 0 = 0
    }

    // This wave's w row into registers: chunk c holds w[row][(c*64+lane)*4 ..+3].
    const float4* wrow4 = (const float4*)(w_in + (size_t)row * NN);
    float4 wreg[CHUNKS];
    #pragma unroll
    for (int c = 0; c < CHUNKS; ++c) wreg[c] = wrow4[c * 64 + lane];

    __syncthreads();

    for (int t = 0; t < T_STEPS; ++t) {
        const int par = t & 1;

        // ---- phase A: owners integrate v, spike, write raster, publish ----
        if (tid < 64) {
            float z = 0.0f;
            if (tid < ROWS_PER_BLOCK) {
                float v = v_own;
                v = v + DT_TAU * ((0.0f - v) + isyn_s8[tid]
                                  + x_s[t * ROWS_PER_BLOCK + tid]);        // LIF
                z = (v - V_TH_C > 0.0f) ? 1.0f : 0.0f;                     // spike
                v_own = v * (1.0f - z);                                    // reset
                tpo_own = tpo_own + TRC * (-tpo_own + z);                  // post-trace
                tpo_s8[tid] = tpo_own;
                // raster: each block writes its own 8 floats (fire-and-forget,
                // overlaps the exchange; no block-0 serialization)
                out[(size_t)t * NN + bid * ROWS_PER_BLOCK + tid] = z;
            }
            if (t + 1 < T_STEPS) {
                unsigned long long bits = __ballot(z > 0.0f) & 0xFFull;
                if (tid == 0) {
                    // message == data: single 4B atomic store; tag (t+1) certifies
                    // payload. Poison 0xAAAAAAAA (tag 0xAAAAAA) and stale tags from
                    // a previous run are destroyed by this run's monotone overwrite
                    // chain before they could ever alias (see parity argument).
                    unsigned word = ((unsigned)(t + 1) << 8) | (unsigned)bits;
                    __hip_atomic_store(&zpub[par * BLOCKS + bid], word,
                                       __ATOMIC_RELAXED, __HIP_MEMORY_SCOPE_AGENT);
                }
            }
        }
        if (t == T_STEPS - 1) break;   // raster[63] written; no exchange needed

        // ---- phase B: wave 1 polls all 256 words, 4 per lane, dwordx4 sweeps ----
        if (wv == 1) {
            const unsigned expect = (unsigned)(t + 1);
            const unsigned* p = zpub + par * BLOCKS + 4 * lane;
            uint4v w;
            bool done = false;
            do {
                asm volatile("global_load_dwordx4 %0, %1, off sc0 sc1\n\t"
                             "s_waitcnt vmcnt(0)"
                             : "=v"(w) : "v"(p) : "memory");
                // tag+payload share a dword -> per-dword atomicity suffices;
                // matched words can't be overwritten until every block published
                // t+1 (parity double-buffer), so the final sweep is a consistent
                // snapshot.
                done = ((w.x >> 8) == expect) & ((w.y >> 8) == expect) &
                       ((w.z >> 8) == expect) & ((w.w >> 8) == expect);
            } while (!done);
            *(uint4v*)&zw_s[4 * lane] = w;
        }
        __syncthreads();

        // unpack spikes, update replicated pre-trace
        {
            unsigned wbits = zw_s[tid >> 1];
            int sh = (tid & 1) * 4;
            float4 z4;
            z4.x = ((wbits >> (sh + 0)) & 1u) ? 1.0f : 0.0f;
            z4.y = ((wbits >> (sh + 1)) & 1u) ? 1.0f : 0.0f;
            z4.z = ((wbits >> (sh + 2)) & 1u) ? 1.0f : 0.0f;
            z4.w = ((wbits >> (sh + 3)) & 1u) ? 1.0f : 0.0f;
            ((float4*)z_s)[tid] = z4;
            tp4.x = tp4.x + TRC * (-tp4.x + z4.x);
            tp4.y = tp4.y + TRC * (-tp4.y + z4.y);
            tp4.z = tp4.z + TRC * (-tp4.z + z4.z);
            tp4.w = tp4.w + TRC * (-tp4.w + z4.w);
            ((float4*)tp_s)[tid] = tp4;
        }
        __syncthreads();

        // ---- phase C: fused STDP w-update (registers) + matvec for t+1 ----
        const float zi   = z_s[row];
        const float tpoi = tpo_s8[wv];
        float acc = 0.0f;
        const float4* z4s  = (const float4*)z_s;
        const float4* tp4s = (const float4*)tp_s;
        #pragma unroll
        for (int c = 0; c < CHUNKS; ++c) {
            float4 zj = z4s[c * 64 + lane];
            float4 tj = tp4s[c * 64 + lane];
            float nw;
            nw = wreg[c].x + (ETA * (zi * tj.x) - ETA * (tpoi * zj.x));
            nw = fminf(fmaxf(nw, 0.0f), 1.0f); wreg[c].x = nw; acc += nw * zj.x;
            nw = wreg[c].y + (ETA * (zi * tj.y) - ETA * (tpoi * zj.y));
            nw = fminf(fmaxf(nw, 0.0f), 1.0f); wreg[c].y = nw; acc += nw * zj.y;
            nw = wreg[c].z + (ETA * (zi * tj.z) - ETA * (tpoi * zj.z));
            nw = fminf(fmaxf(nw, 0.0f), 1.0f); wreg[c].z = nw; acc += nw * zj.z;
            nw = wreg[c].w + (ETA * (zi * tj.w) - ETA * (tpoi * zj.w));
            nw = fminf(fmaxf(nw, 0.0f), 1.0f); wreg[c].w = nw; acc += nw * zj.w;
        }
        #pragma unroll
        for (int m = 32; m >= 1; m >>= 1) acc += __shfl_xor(acc, m, 64);
        if (lane == 0) isyn_s8[wv] = acc;   // i_syn for step t+1 — stays in LDS
        __syncthreads();                    // isyn_s8/tpo/next-A ordering
    }
}

extern "C" void kernel_launch(void* const* d_in, const int* in_sizes, int n_in,
                              void* d_out, int out_size, void* d_ws, size_t ws_size,
                              hipStream_t stream) {
    const float* x     = (const float*)d_in[0];   // [T,N]
    const float* w_in  = (const float*)d_in[1];   // [N,N]
    const float* tpre  = (const float*)d_in[2];   // [N]
    const float* tpost = (const float*)d_in[3];   // [N]
    float*       out   = (float*)d_out;           // [T,N]

    // ws: zpub[2][256] u32 = 2 KB. 0xAA poison (tag 0xAAAAAA) never matches a
    // real tag (1..64), and parity double-buffering prevents overwrite of
    // unconsumed words — no initialization needed at all.
    unsigned* zpub = (unsigned*)d_ws;

    void* args[] = {(void*)&x, (void*)&w_in, (void*)&tpre, (void*)&tpost,
                    (void*)&zpub, (void*)&out};
    hipLaunchCooperativeKernel((void*)snn_msg_kernel,
                               dim3(BLOCKS), dim3(THREADS),
                               args, 0, stream);
}

// Round 2
// 282.279 us; speedup vs baseline: 1.2970x; 1.2970x over previous
//
#include <hip/hip_runtime.h>

// Problem constants (match reference)
constexpr int   T_STEPS = 64;
constexpr int   NN      = 2048;
constexpr float DT_TAU  = 0.1f;    // DT * TAU_MEM_INV
constexpr float V_TH_C  = 1.0f;
constexpr float TRC     = 0.05f;   // DT * TAU_PRE_INV == DT * TAU_POST_INV
constexpr float ETA     = 1e-3f;   // ETA_PLUS == ETA_MINUS

// 256 blocks x 512 threads (cooperative, 1 block/CU). Block b owns neurons
// [8b, 8b+8): their w rows (registers, 32 VGPR/lane), v, tpo. z and tp are
// replicated per block, reconstructed each step from the published spike bits.
//
// Exchange: ONE tagged u64 per block per step ((t+1)<<32 | bits), but each
// word PADDED TO ITS OWN 128B LINE. Rationale (round-1 post-mortem): with all
// 256 words packed on 16-32 lines, every line absorbed ~2048 poll requests
// per sweep (~3.4 req/cy >> 1/cy bank service) — the publish stores queued
// behind that backlog, costing ~3 us/step. With 128B stride each word's line
// serves only 256 pollers (~0.4 req/cy) — unsaturated, store lands at the
// ~500cy visibility floor. s_sleep 1 backoff adds margin.
constexpr int BLOCKS  = 256;
constexpr int THREADS = 512;
constexpr int ROWS_PER_BLOCK = NN / BLOCKS;   // 8
constexpr int CHUNKS = NN / 256;              // 8 float4 chunks per lane

__global__ __launch_bounds__(THREADS)
void snn_msg_kernel(const float* __restrict__ x,       // [T, N]
                    const float* __restrict__ w_in,    // [N, N] pristine (never written)
                    const float* __restrict__ tpre0,   // [N]
                    const float* __restrict__ tpost0,  // [N]
                    unsigned long long* __restrict__ zpub, // [2][BLOCKS*stride]
                    int stride,                        // u64 units between words
                    float*       __restrict__ out)     // [T, N] spikes
{
    const int bid  = blockIdx.x;
    const int tid  = threadIdx.x;
    const int wv   = tid >> 6;
    const int lane = tid & 63;
    const int row  = bid * ROWS_PER_BLOCK + wv;   // this wave's w row / owned neuron

    __shared__ __align__(16) float z_s[NN];       // replicated spike vector
    __shared__ __align__(16) float tp_s[NN];      // replicated pre-trace
    __shared__ __align__(16) float x_s[T_STEPS * ROWS_PER_BLOCK]; // owned inputs (2 KB)
    __shared__ unsigned zw_s[BLOCKS];             // polled spike words
    __shared__ float tpo_s8[ROWS_PER_BLOCK];      // owned post-traces
    __shared__ float isyn_s8[ROWS_PER_BLOCK];     // owned synaptic currents (local!)

    // Replicated tp in registers (neurons 4*tid..4*tid+3), mirrored to LDS.
    float4 tp4 = ((const float4*)tpre0)[tid];
    ((float4*)tp_s)[tid] = tp4;

    // Stage ALL owned inputs x[t][8b..8b+8) into LDS once: no per-step global
    // load on wave 0's critical path.
    x_s[tid] = x[(size_t)(tid >> 3) * NN + bid * ROWS_PER_BLOCK + (tid & 7)];

    // Owner state on threads 0..7 (wave 0): v, tpo.
    float v_own = 0.0f, tpo_own = 0.0f;
    if (tid < ROWS_PER_BLOCK) {
        tpo_own = tpost0[bid * ROWS_PER_BLOCK + tid];
        isyn_s8[tid] = 0.0f;                       // step 0: i_syn = w @ 0 = 0
    }

    // This wave's w row into registers: chunk c holds w[row][(c*64+lane)*4 ..+3].
    const float4* wrow4 = (const float4*)(w_in + (size_t)row * NN);
    float4 wreg[CHUNKS];
    #pragma unroll
    for (int c = 0; c < CHUNKS; ++c) wreg[c] = wrow4[c * 64 + lane];

    __syncthreads();

    for (int t = 0; t < T_STEPS; ++t) {
        const int par = t & 1;

        // ---- phase A: owners integrate v, spike, publish FIRST, then raster ----
        if (tid < 64) {
            float z = 0.0f;
            float v = 0.0f;
            if (tid < ROWS_PER_BLOCK) {
                v = v_own;
                v = v + DT_TAU * ((0.0f - v) + isyn_s8[tid]
                                  + x_s[t * ROWS_PER_BLOCK + tid]);        // LIF
                z = (v - V_TH_C > 0.0f) ? 1.0f : 0.0f;                     // spike
            }
            unsigned long long bits = __ballot(z > 0.0f) & 0xFFull;
            if (t + 1 < T_STEPS && tid == 0) {
                // message == data: single 8B atomic store, tag (t+1) certifies
                // payload. Tag 1..64 never matches 0x00000000 or 0xAAAAAAAA
                // poison; parity double-buffering prevents overwrite of
                // unconsumed words — no ws initialization needed.
                unsigned long long word =
                    ((unsigned long long)(unsigned)(t + 1) << 32) | bits;
                __hip_atomic_store(&zpub[(size_t)(par * BLOCKS + bid) * stride],
                                   word, __ATOMIC_RELAXED,
                                   __HIP_MEMORY_SCOPE_AGENT);
            }
            if (tid < ROWS_PER_BLOCK) {
                // bookkeeping AFTER the publish store is issued
                v_own   = v * (1.0f - z);                                  // reset
                tpo_own = tpo_own + TRC * (-tpo_own + z);                  // post-trace
                tpo_s8[tid] = tpo_own;
                // raster: each block writes its own 8 floats (32B contiguous,
                // fire-and-forget, overlaps the exchange)
                out[(size_t)t * NN + bid * ROWS_PER_BLOCK + tid] = z;
            }
        }
        if (t == T_STEPS - 1) break;   // raster[63] written; no exchange needed

        // ---- phase B: 256 threads poll one word each (own 128B line) ----
        if (tid < BLOCKS) {
            const unsigned long long* p =
                &zpub[(size_t)(par * BLOCKS + tid) * stride];
            unsigned long long v =
                __hip_atomic_load(p, __ATOMIC_RELAXED, __HIP_MEMORY_SCOPE_AGENT);
            while ((unsigned)(v >> 32) != (unsigned)(t + 1)) {
                asm volatile("s_sleep 1");   // ~64cy backoff: keeps line queues
                                             // unsaturated, adds <30ns latency
                v = __hip_atomic_load(p, __ATOMIC_RELAXED,
                                      __HIP_MEMORY_SCOPE_AGENT);
            }
            zw_s[tid] = (unsigned)v;   // low 8 bits = z of neurons 8*tid..8*tid+7
        }
        __syncthreads();

        // unpack spikes, update replicated pre-trace
        {
            unsigned wbits = zw_s[tid >> 1];
            int sh = (tid & 1) * 4;
            float4 z4;
            z4.x = ((wbits >> (sh + 0)) & 1u) ? 1.0f : 0.0f;
            z4.y = ((wbits >> (sh + 1)) & 1u) ? 1.0f : 0.0f;
            z4.z = ((wbits >> (sh + 2)) & 1u) ? 1.0f : 0.0f;
            z4.w = ((wbits >> (sh + 3)) & 1u) ? 1.0f : 0.0f;
            ((float4*)z_s)[tid] = z4;
            tp4.x = tp4.x + TRC * (-tp4.x + z4.x);
            tp4.y = tp4.y + TRC * (-tp4.y + z4.y);
            tp4.z = tp4.z + TRC * (-tp4.z + z4.z);
            tp4.w = tp4.w + TRC * (-tp4.w + z4.w);
            ((float4*)tp_s)[tid] = tp4;
        }
        __syncthreads();

        // ---- phase C: fused STDP w-update (registers) + matvec for t+1 ----
        // NOTE: arithmetic form kept EXACTLY as the bit-exact baseline
        // (absmax 0.0) — do not refactor into FMA (rounding would drift w and
        // can flip borderline spikes).
        const float zi   = z_s[row];
        const float tpoi = tpo_s8[wv];
        float acc = 0.0f;
        const float4* z4s  = (const float4*)z_s;
        const float4* tp4s = (const float4*)tp_s;
        #pragma unroll
        for (int c = 0; c < CHUNKS; ++c) {
            float4 zj = z4s[c * 64 + lane];
            float4 tj = tp4s[c * 64 + lane];
            float nw;
            nw = wreg[c].x + (ETA * (zi * tj.x) - ETA * (tpoi * zj.x));
            nw = fminf(fmaxf(nw, 0.0f), 1.0f); wreg[c].x = nw; acc += nw * zj.x;
            nw = wreg[c].y + (ETA * (zi * tj.y) - ETA * (tpoi * zj.y));
            nw = fminf(fmaxf(nw, 0.0f), 1.0f); wreg[c].y = nw; acc += nw * zj.y;
            nw = wreg[c].z + (ETA * (zi * tj.z) - ETA * (tpoi * zj.z));
            nw = fminf(fmaxf(nw, 0.0f), 1.0f); wreg[c].z = nw; acc += nw * zj.z;
            nw = wreg[c].w + (ETA * (zi * tj.w) - ETA * (tpoi * zj.w));
            nw = fminf(fmaxf(nw, 0.0f), 1.0f); wreg[c].w = nw; acc += nw * zj.w;
        }
        #pragma unroll
        for (int m = 32; m >= 1; m >>= 1) acc += __shfl_xor(acc, m, 64);
        if (lane == 0) isyn_s8[wv] = acc;   // i_syn for step t+1 — stays in LDS
        __syncthreads();                    // isyn_s8/tpo/next-A ordering
    }
}

extern "C" void kernel_launch(void* const* d_in, const int* in_sizes, int n_in,
                              void* d_out, int out_size, void* d_ws, size_t ws_size,
                              hipStream_t stream) {
    const float* x     = (const float*)d_in[0];   // [T,N]
    const float* w_in  = (const float*)d_in[1];   // [N,N]
    const float* tpre  = (const float*)d_in[2];   // [N]
    const float* tpost = (const float*)d_in[3];   // [N]
    float*       out   = (float*)d_out;           // [T,N]

    unsigned long long* zpub = (unsigned long long*)d_ws;

    // Pad each published word to its own line if the workspace allows:
    // 128B stride (TCC line) needs 64KB, 64B needs 32KB, else packed (4KB).
    int stride;
    if      (ws_size >= (size_t)2 * BLOCKS * 16 * sizeof(unsigned long long)) stride = 16;
    else if (ws_size >= (size_t)2 * BLOCKS *  8 * sizeof(unsigned long long)) stride = 8;
    else                                                                      stride = 1;

    void* args[] = {(void*)&x, (void*)&w_in, (void*)&tpre, (void*)&tpost,
                    (void*)&zpub, (void*)&stride, (void*)&out};
    hipLaunchCooperativeKernel((void*)snn_msg_kernel,
                               dim3(BLOCKS), dim3(THREADS),
                               args, 0, stream);
}